// Round 18
// baseline (160.661 us; speedup 1.0000x reference)
//
#include <hip/hip_runtime.h>
#include <hip/hip_bf16.h>

typedef unsigned short u16;
typedef __bf16 bf16x8 __attribute__((ext_vector_type(8)));
typedef float f32x4 __attribute__((ext_vector_type(4)));
typedef float f32x16 __attribute__((ext_vector_type(16)));
typedef unsigned short u16x8 __attribute__((ext_vector_type(8)));
typedef unsigned short u16x4 __attribute__((ext_vector_type(4)));

// S=128, R=256, CM=256, CZ=128, H=8, HD=32
#define LOG2E 1.4426950408889634f

__device__ __forceinline__ u16 f2b(float f) {          // native HW bf16 cvt (RNE)
  union { __bf16 b; u16 u; } v; v.b = (__bf16)f; return v.u;
}
__device__ __forceinline__ float bf2f(u16 u) {
  union { unsigned u; float f; } v; v.u = ((unsigned)u) << 16;
  return v.f;
}
__device__ __forceinline__ float fexp2(float x) {      // 1 instr, hazard-safe
  return __builtin_amdgcn_exp2f(x);
}

// ---------------------------------------------------------------------------
// Kernel 0 (MERGED pre-pass): blocks [0,80) = weight pack (B-frag order);
// [80,4176) = pair bias (pre-scaled LOG2E, permuted); [4176,12368) =
// LayerNorm(m) -> bf16 PACKED in MFMA A-fragment order.
__global__ __launch_bounds__(256) void k_pre(
    const float* __restrict__ wq, const float* __restrict__ wk,
    const float* __restrict__ wv, const float* __restrict__ wg,
    const float* __restrict__ wo, u16* __restrict__ wtp,
    const float* __restrict__ z, const float* __restrict__ zg,
    const float* __restrict__ zb, const float* __restrict__ wz,
    float* __restrict__ pbp,
    const float* __restrict__ m, const float* __restrict__ gam,
    const float* __restrict__ bet, u16* __restrict__ mlp) {
  __shared__ float lt[64][68];
  const int b = blockIdx.x;
  const int t = threadIdx.x;
  if (b < 80) {
    const int widx = b >> 4;
    const int tid = b & 15;
    const int ri = (tid >> 2) * 64, ci = (tid & 3) * 64;
    const float* src = (widx == 0) ? wq : (widx == 1) ? wk : (widx == 2) ? wv
                      : (widx == 3) ? wg : wo;
    {
      const int r = t >> 2;
      #pragma unroll
      for (int i = 0; i < 4; ++i) {
        const int c = (t & 3) * 16 + i * 4;
        *(float4*)&lt[r][c] = *(const float4*)&src[(ri + r) * 256 + ci + c];
      }
    }
    __syncthreads();
    #pragma unroll
    for (int cc = 0; cc < 2; ++cc) {
      const int c = t + cc * 256;
      const int kb = c >> 8, cb = (c >> 6) & 3, lg = (c >> 4) & 3, lr = c & 15;
      u16x8 o;
      #pragma unroll
      for (int j = 0; j < 8; ++j) o[j] = f2b(lt[kb * 32 + lg * 8 + j][cb * 16 + lr]);
      const size_t idx = (size_t)widx * 65536 + (size_t)((ci >> 4) + cb) * 4096
                       + (size_t)((ri >> 5) + kb) * 512 + (size_t)(lg * 16 + lr) * 8;
      *(u16x8*)&wtp[idx] = o;
    }
  } else if (b < 4176) {
    const int lane = t & 63, wave = t >> 6;
    const int ql = lane & 15;
    const int p = (b - 80) * 16 + wave * 4 + (lane >> 4);
    const float4 zv0 = *(const float4*)(z + (size_t)p * 128 + ql * 8);
    const float4 zv1 = *(const float4*)(z + (size_t)p * 128 + ql * 8 + 4);
    float s = zv0.x + zv0.y + zv0.z + zv0.w + zv1.x + zv1.y + zv1.z + zv1.w;
    float sq = zv0.x * zv0.x + zv0.y * zv0.y + zv0.z * zv0.z + zv0.w * zv0.w
             + zv1.x * zv1.x + zv1.y * zv1.y + zv1.z * zv1.z + zv1.w * zv1.w;
    #pragma unroll
    for (int o = 8; o > 0; o >>= 1) { s += __shfl_xor(s, o); sq += __shfl_xor(sq, o); }
    const float mu = s * 0.0078125f;
    const float var = sq * 0.0078125f - mu * mu;
    const float rs = rsqrtf(var + 1e-5f);
    const int c0 = ql * 8;
    float zn[8];
    zn[0] = (zv0.x - mu) * rs * zg[c0 + 0] + zb[c0 + 0];
    zn[1] = (zv0.y - mu) * rs * zg[c0 + 1] + zb[c0 + 1];
    zn[2] = (zv0.z - mu) * rs * zg[c0 + 2] + zb[c0 + 2];
    zn[3] = (zv0.w - mu) * rs * zg[c0 + 3] + zb[c0 + 3];
    zn[4] = (zv1.x - mu) * rs * zg[c0 + 4] + zb[c0 + 4];
    zn[5] = (zv1.y - mu) * rs * zg[c0 + 5] + zb[c0 + 5];
    zn[6] = (zv1.z - mu) * rs * zg[c0 + 6] + zb[c0 + 6];
    zn[7] = (zv1.w - mu) * rs * zg[c0 + 7] + zb[c0 + 7];
    float a[8] = {};
    #pragma unroll
    for (int i = 0; i < 8; ++i) {
      #pragma unroll
      for (int hh = 0; hh < 8; ++hh) a[hh] += zn[i] * wz[(c0 + i) * 8 + hh];
    }
    #pragma unroll
    for (int hh = 0; hh < 8; ++hh) {
      #pragma unroll
      for (int o = 8; o > 0; o >>= 1) a[hh] += __shfl_xor(a[hh], o);
    }
    if (ql == 0) {
      const int i = p >> 8, j = p & 255;
      const int strip = i >> 5, il = i & 31, jt = j >> 5, r = j & 31;
      const int gh = (r >> 2) & 1, qd = r >> 3, c4 = r & 3;
      const int off = (strip * 8 + jt) * 1024 + (gh * 32 + il) * 16 + qd * 4 + c4;
      #pragma unroll
      for (int hh = 0; hh < 8; ++hh)
        pbp[(size_t)hh * 65536 + off] = a[hh] * LOG2E;
    }
  } else {
    // ---- LayerNorm(m) -> PACKED A-fragment layout
    const int lane = t & 63;
    const size_t row = (size_t)(b - 4176) * 4 + (t >> 6);
    const float4 xv = *(const float4*)(m + row * 256 + lane * 4);
    float s = xv.x + xv.y + xv.z + xv.w;
    float sq = xv.x * xv.x + xv.y * xv.y + xv.z * xv.z + xv.w * xv.w;
    #pragma unroll
    for (int o = 32; o > 0; o >>= 1) { s += __shfl_xor(s, o); sq += __shfl_xor(sq, o); }
    const float mu = s * 0.00390625f;
    const float var = sq * 0.00390625f - mu * mu;
    const float rs = rsqrtf(var + 1e-5f);
    const int c = lane * 4;
    u16x4 o4;
    o4.x = f2b((xv.x - mu) * rs * gam[c] + bet[c]);
    o4.y = f2b((xv.y - mu) * rs * gam[c + 1] + bet[c + 1]);
    o4.z = f2b((xv.z - mu) * rs * gam[c + 2] + bet[c + 2]);
    o4.w = f2b((xv.w - mu) * rs * gam[c + 3] + bet[c + 3]);
    const size_t ss = row >> 8;
    const int rloc = (int)(row & 255);
    const int ch = rloc >> 5, il = rloc & 31;
    const size_t dst = ss * 65536 + (size_t)ch * 8192 + (size_t)(lane >> 2) * 512
                     + (size_t)(((lane >> 1) & 1) * 32 + il) * 8 + (lane & 1) * 4;
    *(u16x4*)&mlp[dst] = o4;
  }
}

// ---------------------------------------------------------------------------
// Kernel 1 (FUSED v7): 512 threads / 8 waves; one block per (s,h).
// vs R17: (a) XCD-pinned decode h=bid&7 (all blocks of head h on XCD h ->
// pbp/wtp slices L2-resident); (b) s_setprio(1) around MFMA clusters (T5);
// (c) 1-deep pbq prefetch in the attention jt loop (16 VGPR).
__global__ __launch_bounds__(512, 4) void k_fused(
    const u16* __restrict__ mlp, const u16* __restrict__ wtp,
    const float* __restrict__ bg, const float* __restrict__ pbp,
    const float* __restrict__ mask, u16* __restrict__ go) {
  __shared__ u16 gP[256 * 32];     // 16KB gate park
  __shared__ u16 lQ[256 * 32];     // 16KB row-swizzled
  __shared__ u16 lK[256 * 32];     // 16KB
  __shared__ u16 lVt[32][276];     // 17.25KB V^T padded
  __shared__ float lMb[256];
  __shared__ float lL[8][32];
  const int bid = blockIdx.x;
  const int h = bid & 7, s = bid >> 3;   // XCD-pinned: head h -> XCD h
  const int t = threadIdx.x;
  const int lane = t & 63, wave = t >> 6;
  const int il = lane & 31, gh = lane >> 5;
  const int z = wave >> 1, half = wave & 1;

  // B preload: weight slice for z (cols h*32..+31, K=256)
  const u16* Wb = wtp + (size_t)z * 65536 + (size_t)(2 * h + (il >> 4)) * 4096
                + gh * 128 + (il & 15) * 8;
  bf16x8 B[16];
  #pragma unroll
  for (int kc = 0; kc < 16; ++kc) B[kc] = *(const bf16x8*)&Wb[kc * 256];

  if (t < 256)
    lMb[t] = (LOG2E * 1e9f) * (mask[s * 256 + t] - 1.0f) - 24.0f;  // log2 + shift
  const float bgv = bg[h * 32 + il];
  const u16* Ab = mlp + (size_t)s * 65536 + (size_t)lane * 8;

  // ---- GEMM phase: 4 chunks per wave, barrier-free, coalesced A from L2
  #pragma unroll
  for (int cc = 0; cc < 4; ++cc) {
    const int c = half * 4 + cc;
    f32x16 a0 = {}, a1 = {};
    bf16x8 A0[8];
    #pragma unroll
    for (int kc = 0; kc < 8; ++kc)
      A0[kc] = *(const bf16x8*)&Ab[c * 8192 + kc * 512];
    __builtin_amdgcn_s_setprio(1);
    #pragma unroll
    for (int kc = 0; kc < 8; kc += 2) {
      a0 = __builtin_amdgcn_mfma_f32_32x32x16_bf16(A0[kc], B[kc], a0, 0, 0, 0);
      a1 = __builtin_amdgcn_mfma_f32_32x32x16_bf16(A0[kc + 1], B[kc + 1], a1, 0, 0, 0);
    }
    __builtin_amdgcn_s_setprio(0);
    bf16x8 A1[8];
    #pragma unroll
    for (int kc = 0; kc < 8; ++kc)
      A1[kc] = *(const bf16x8*)&Ab[c * 8192 + (kc + 8) * 512];
    __builtin_amdgcn_s_setprio(1);
    #pragma unroll
    for (int kc = 0; kc < 8; kc += 2) {
      a0 = __builtin_amdgcn_mfma_f32_32x32x16_bf16(A1[kc], B[kc + 8], a0, 0, 0, 0);
      a1 = __builtin_amdgcn_mfma_f32_32x32x16_bf16(A1[kc + 1], B[kc + 9], a1, 0, 0, 0);
    }
    __builtin_amdgcn_s_setprio(0);
    const f32x16 acc = a0 + a1;
    // D[row][col=il], row = (reg&3) + 8*(reg>>2) + 4*gh  (within chunk)
    if (z == 0) {            // Q scaled by (1/sqrt32)*LOG2E
      #pragma unroll
      for (int reg = 0; reg < 16; ++reg) {
        const int R = c * 32 + (reg & 3) + 8 * (reg >> 2) + 4 * gh;
        *(u16*)((char*)lQ + ((R * 64 + il * 2) ^ ((R & 7) << 4))) =
            f2b(acc[reg] * (0.17677669529663687f * LOG2E));
      }
    } else if (z == 1) {     // K
      #pragma unroll
      for (int reg = 0; reg < 16; ++reg) {
        const int R = c * 32 + (reg & 3) + 8 * (reg >> 2) + 4 * gh;
        *(u16*)((char*)lK + ((R * 64 + il * 2) ^ ((R & 7) << 4))) = f2b(acc[reg]);
      }
    } else if (z == 2) {     // V -> V^T
      #pragma unroll
      for (int reg = 0; reg < 16; ++reg) {
        const int R = c * 32 + (reg & 3) + 8 * (reg >> 2) + 4 * gh;
        lVt[il][R] = f2b(acc[reg]);
      }
    } else {                 // G = sigmoid(x+bg) -> LDS park
      #pragma unroll
      for (int reg = 0; reg < 16; ++reg) {
        const int R = c * 32 + (reg & 3) + 8 * (reg >> 2) + 4 * gh;
        const float x = acc[reg] + bgv;
        gP[R * 32 + il] = f2b(1.0f / (1.0f + __expf(-x)));
      }
    }
  }
  __syncthreads();   // lQ/lK/lVt/gP visible to all waves

  // ---- Attention phase: ONE strip (32 q-rows) per wave; 1-deep pbq prefetch
  {
    const int i0 = wave * 32;
    bf16x8 qf[2];
    #pragma unroll
    for (int kk = 0; kk < 2; ++kk) {
      const int row = i0 + il;
      qf[kk] = *(const bf16x8*)((const char*)lQ +
          ((row * 64 + (kk * 16 + gh * 8) * 2) ^ ((row & 7) << 4)));
    }
    const float* pbt = pbp + ((size_t)h * 8 + wave) * 8192 + lane * 16;

    f32x16 oacc0 = {}, oacc1 = {};
    float s0 = 0.f, s1 = 0.f, s2 = 0.f, s3 = 0.f;

    f32x4 pq0 = *(const f32x4*)&pbt[0];
    f32x4 pq1 = *(const f32x4*)&pbt[4];
    f32x4 pq2 = *(const f32x4*)&pbt[8];
    f32x4 pq3 = *(const f32x4*)&pbt[12];

    #pragma unroll
    for (int jt = 0; jt < 8; ++jt) {
      f32x4 pn0, pn1, pn2, pn3;
      if (jt < 7) {
        const float* pl = pbt + (jt + 1) * 1024;
        pn0 = *(const f32x4*)&pl[0];
        pn1 = *(const f32x4*)&pl[4];
        pn2 = *(const f32x4*)&pl[8];
        pn3 = *(const f32x4*)&pl[12];
      }
      f32x16 c;
      {
        const f32x4 mb0 = *(const f32x4*)&lMb[jt * 32 + 0 * 8 + gh * 4];
        const f32x4 mb1 = *(const f32x4*)&lMb[jt * 32 + 1 * 8 + gh * 4];
        const f32x4 mb2 = *(const f32x4*)&lMb[jt * 32 + 2 * 8 + gh * 4];
        const f32x4 mb3 = *(const f32x4*)&lMb[jt * 32 + 3 * 8 + gh * 4];
        #pragma unroll
        for (int c4 = 0; c4 < 4; ++c4) {
          c[0 * 4 + c4] = pq0[c4] + mb0[c4];
          c[1 * 4 + c4] = pq1[c4] + mb1[c4];
          c[2 * 4 + c4] = pq2[c4] + mb2[c4];
          c[3 * 4 + c4] = pq3[c4] + mb3[c4];
        }
      }
      const int krow = jt * 32 + il;
      const bf16x8 kf0 = *(const bf16x8*)((const char*)lK +
          ((krow * 64 + (gh * 8) * 2) ^ ((krow & 7) << 4)));
      const bf16x8 kf1 = *(const bf16x8*)((const char*)lK +
          ((krow * 64 + (16 + gh * 8) * 2) ^ ((krow & 7) << 4)));
      __builtin_amdgcn_s_setprio(1);
      c = __builtin_amdgcn_mfma_f32_32x32x16_bf16(kf0, qf[0], c, 0, 0, 0);
      c = __builtin_amdgcn_mfma_f32_32x32x16_bf16(kf1, qf[1], c, 0, 0, 0);
      __builtin_amdgcn_s_setprio(0);
      union PK { __bf16 h[4]; uint2 u; } pk[4];
      #pragma unroll
      for (int qd = 0; qd < 4; ++qd) {
        const float p0 = fexp2(c[qd * 4 + 0]);
        const float p1 = fexp2(c[qd * 4 + 1]);
        const float p2 = fexp2(c[qd * 4 + 2]);
        const float p3 = fexp2(c[qd * 4 + 3]);
        s0 += p0; s1 += p1; s2 += p2; s3 += p3;
        pk[qd].h[0] = (__bf16)p0; pk[qd].h[1] = (__bf16)p1;
        pk[qd].h[2] = (__bf16)p2; pk[qd].h[3] = (__bf16)p3;
      }
      const uint2 sA = gh ? pk[0].u : pk[1].u;
      uint2 rA; rA.x = __shfl_xor(sA.x, 32); rA.y = __shfl_xor(sA.y, 32);
      const uint2 sB = gh ? pk[2].u : pk[3].u;
      uint2 rB; rB.x = __shfl_xor(sB.x, 32); rB.y = __shfl_xor(sB.y, 32);
      union FR { uint2 u2[2]; bf16x8 v; } fa0, fa1;
      fa0.u2[0] = gh ? rA : pk[0].u;
      fa0.u2[1] = gh ? pk[1].u : rA;
      fa1.u2[0] = gh ? rB : pk[2].u;
      fa1.u2[1] = gh ? pk[3].u : rB;
      const bf16x8 vf0 = *(const bf16x8*)&lVt[il][jt * 32 + gh * 8];
      const bf16x8 vf1 = *(const bf16x8*)&lVt[il][jt * 32 + 16 + gh * 8];
      __builtin_amdgcn_s_setprio(1);
      oacc0 = __builtin_amdgcn_mfma_f32_32x32x16_bf16(fa0.v, vf0, oacc0, 0, 0, 0);
      oacc1 = __builtin_amdgcn_mfma_f32_32x32x16_bf16(fa1.v, vf1, oacc1, 0, 0, 0);
      __builtin_amdgcn_s_setprio(0);
      if (jt < 7) { pq0 = pn0; pq1 = pn1; pq2 = pn2; pq3 = pn3; }
    }

    float lsum = (s0 + s1) + (s2 + s3);
    lsum += __shfl_xor(lsum, 32);
    if (lane < 32) lL[wave][il] = 1.0f / lsum;

    #pragma unroll
    for (int qd = 0; qd < 4; ++qd) {
      const f32x4 invq = *(const f32x4*)&lL[wave][qd * 8 + gh * 4];
      #pragma unroll
      for (int c4 = 0; c4 < 4; ++c4) {
        const int iloc = qd * 8 + gh * 4 + c4;
        const size_t row = (size_t)s * 256 + i0 + iloc;
        const int col = h * 32 + il;
        const float ov = (oacc0[qd * 4 + c4] + oacc1[qd * 4 + c4]) * invq[c4];
        const float gv = bf2f(gP[(i0 + iloc) * 32 + il]);
        go[row * 256 + col] = f2b(gv * ov);
      }
    }
  }
}

// ---------------------------------------------------------------------------
// Kernel 2: out = go @ wo + bo. grid 1024: 32 rows x 256 cols. Unchanged.
__global__ __launch_bounds__(256, 4) void k_gemm_out(
    const u16* __restrict__ go, const u16* __restrict__ wop,
    const float* __restrict__ bo, float* __restrict__ out) {
  __shared__ u16 lA[32 * 256];
  const int t = threadIdx.x;
  const size_t row0 = (size_t)blockIdx.x * 32;
  const int lane = t & 63, wave = t >> 6;
  const u16* Wz = wop + (size_t)wave * 16384 + (size_t)lane * 8;
  u16x8 areg[4];
  #pragma unroll
  for (int i = 0; i < 4; ++i)
    areg[i] = *(const u16x8*)&go[(row0 + i * 8 + (t >> 5)) * 256 + (t & 31) * 8];
  bf16x8 B[4][4];
  #pragma unroll
  for (int kc = 0; kc < 4; ++kc) {
    #pragma unroll
    for (int nn = 0; nn < 4; ++nn)
      B[kc][nn] = *(const bf16x8*)&Wz[nn * 4096 + kc * 512];
  }
  __builtin_amdgcn_sched_barrier(0);
  #pragma unroll
  for (int i = 0; i < 4; ++i) {
    const int r = i * 8 + (t >> 5);
    const int c = (t & 31) * 8;
    *(u16x8*)((char*)lA + ((r * 512 + c * 2) ^ ((r & 7) << 4))) = areg[i];
  }
  __syncthreads();
  const int lrow = lane & 15, lg = lane >> 4;
  f32x4 acc[2][4] = {};
  #pragma unroll
  for (int kc = 0; kc < 4; ++kc) {
    bf16x8 af[2];
    #pragma unroll
    for (int mm = 0; mm < 2; ++mm) {
      const int row = mm * 16 + lrow;
      af[mm] = *(const bf16x8*)((const char*)lA +
          ((row * 512 + kc * 64 + lg * 16) ^ ((row & 7) << 4)));
    }
    #pragma unroll
    for (int mm = 0; mm < 2; ++mm) {
      #pragma unroll
      for (int nn = 0; nn < 4; ++nn)
        acc[mm][nn] = __builtin_amdgcn_mfma_f32_16x16x32_bf16(
            af[mm], B[kc][nn], acc[mm][nn], 0, 0, 0);
    }
  }
  #pragma unroll
  for (int kc = 0; kc < 4; ++kc) {
    #pragma unroll
    for (int nn = 0; nn < 4; ++nn)
      B[kc][nn] = *(const bf16x8*)&Wz[nn * 4096 + (kc + 4) * 512];
  }
  __builtin_amdgcn_sched_barrier(0);
  #pragma unroll
  for (int kc = 0; kc < 4; ++kc) {
    bf16x8 af[2];
    #pragma unroll
    for (int mm = 0; mm < 2; ++mm) {
      const int row = mm * 16 + lrow;
      af[mm] = *(const bf16x8*)((const char*)lA +
          ((row * 512 + (kc + 4) * 64 + lg * 16) ^ ((row & 7) << 4)));
    }
    #pragma unroll
    for (int mm = 0; mm < 2; ++mm) {
      #pragma unroll
      for (int nn = 0; nn < 4; ++nn)
        acc[mm][nn] = __builtin_amdgcn_mfma_f32_16x16x32_bf16(
            af[mm], B[kc][nn], acc[mm][nn], 0, 0, 0);
    }
  }
  const int wc = wave * 64, lg4 = lg * 4;
  #pragma unroll
  for (int mm = 0; mm < 2; ++mm) {
    #pragma unroll
    for (int nn = 0; nn < 4; ++nn) {
      const int col = wc + nn * 16 + lrow;
      #pragma unroll
      for (int jr = 0; jr < 4; ++jr) {
        const size_t row = row0 + mm * 16 + lg4 + jr;
        out[row * 256 + col] = acc[mm][nn][jr] + bo[col];
      }
    }
  }
}

// ---------------------------------------------------------------------------
extern "C" void kernel_launch(void* const* d_in, const int* in_sizes, int n_in,
                              void* d_out, int out_size, void* d_ws, size_t ws_size,
                              hipStream_t stream) {
  const float* m      = (const float*)d_in[0];
  const float* z      = (const float*)d_in[1];
  const float* mask   = (const float*)d_in[2];
  const float* ln_m_g = (const float*)d_in[3];
  const float* ln_m_b = (const float*)d_in[4];
  const float* ln_z_g = (const float*)d_in[5];
  const float* ln_z_b = (const float*)d_in[6];
  const float* w_z    = (const float*)d_in[7];
  const float* wq     = (const float*)d_in[8];
  const float* wk     = (const float*)d_in[9];
  const float* wv     = (const float*)d_in[10];
  const float* wg     = (const float*)d_in[11];
  const float* bg     = (const float*)d_in[12];
  const float* wo     = (const float*)d_in[13];
  const float* bo     = (const float*)d_in[14];
  float* out = (float*)d_out;

  char* w = (char*)d_ws;
  u16* wtp   = (u16*)w;   w += (size_t)5 * 65536 * 2;
  float* pbp = (float*)w; w += (size_t)8 * 65536 * 4;
  u16* mlp   = (u16*)w;   w += (size_t)32768 * 256 * 2;
  u16* gow   = (u16*)w;   w += (size_t)32768 * 256 * 2;

  k_pre      <<<12368, 256, 0, stream>>>(wq, wk, wv, wg, wo, wtp,
                                         z, ln_z_g, ln_z_b, w_z, pbp,
                                         m, ln_m_g, ln_m_b, mlp);
  k_fused    <<<1024, 512, 0, stream>>>(mlp, wtp, bg, pbp, mask, gow);
  k_gemm_out <<<1024, 256, 0, stream>>>(gow, wtp + (size_t)4 * 65536, bo, out);
}

// Round 19
// 151.092 us; speedup vs baseline: 1.0633x; 1.0633x over previous
//
#include <hip/hip_runtime.h>
#include <hip/hip_bf16.h>

typedef unsigned short u16;
typedef __bf16 bf16x8 __attribute__((ext_vector_type(8)));
typedef float f32x4 __attribute__((ext_vector_type(4)));
typedef float f32x16 __attribute__((ext_vector_type(16)));
typedef unsigned short u16x8 __attribute__((ext_vector_type(8)));
typedef unsigned short u16x4 __attribute__((ext_vector_type(4)));

// S=128, R=256, CM=256, CZ=128, H=8, HD=32
#define LOG2E 1.4426950408889634f

__device__ __forceinline__ u16 f2b(float f) {          // native HW bf16 cvt (RNE)
  union { __bf16 b; u16 u; } v; v.b = (__bf16)f; return v.u;
}
__device__ __forceinline__ float bf2f(u16 u) {
  union { unsigned u; float f; } v; v.u = ((unsigned)u) << 16;
  return v.f;
}
__device__ __forceinline__ float fexp2(float x) {      // 1 instr, hazard-safe
  return __builtin_amdgcn_exp2f(x);
}

// ---------------------------------------------------------------------------
// Kernel 0 (MERGED pre-pass): blocks [0,80) = weight pack (B-frag order);
// [80,4176) = pair bias (pre-scaled LOG2E, permuted); [4176,12368) =
// LayerNorm(m) -> bf16 PACKED in MFMA A-fragment order.
__global__ __launch_bounds__(256) void k_pre(
    const float* __restrict__ wq, const float* __restrict__ wk,
    const float* __restrict__ wv, const float* __restrict__ wg,
    const float* __restrict__ wo, u16* __restrict__ wtp,
    const float* __restrict__ z, const float* __restrict__ zg,
    const float* __restrict__ zb, const float* __restrict__ wz,
    float* __restrict__ pbp,
    const float* __restrict__ m, const float* __restrict__ gam,
    const float* __restrict__ bet, u16* __restrict__ mlp) {
  __shared__ float lt[64][68];
  const int b = blockIdx.x;
  const int t = threadIdx.x;
  if (b < 80) {
    const int widx = b >> 4;
    const int tid = b & 15;
    const int ri = (tid >> 2) * 64, ci = (tid & 3) * 64;
    const float* src = (widx == 0) ? wq : (widx == 1) ? wk : (widx == 2) ? wv
                      : (widx == 3) ? wg : wo;
    {
      const int r = t >> 2;
      #pragma unroll
      for (int i = 0; i < 4; ++i) {
        const int c = (t & 3) * 16 + i * 4;
        *(float4*)&lt[r][c] = *(const float4*)&src[(ri + r) * 256 + ci + c];
      }
    }
    __syncthreads();
    #pragma unroll
    for (int cc = 0; cc < 2; ++cc) {
      const int c = t + cc * 256;
      const int kb = c >> 8, cb = (c >> 6) & 3, lg = (c >> 4) & 3, lr = c & 15;
      u16x8 o;
      #pragma unroll
      for (int j = 0; j < 8; ++j) o[j] = f2b(lt[kb * 32 + lg * 8 + j][cb * 16 + lr]);
      const size_t idx = (size_t)widx * 65536 + (size_t)((ci >> 4) + cb) * 4096
                       + (size_t)((ri >> 5) + kb) * 512 + (size_t)(lg * 16 + lr) * 8;
      *(u16x8*)&wtp[idx] = o;
    }
  } else if (b < 4176) {
    const int lane = t & 63, wave = t >> 6;
    const int ql = lane & 15;
    const int p = (b - 80) * 16 + wave * 4 + (lane >> 4);
    const float4 zv0 = *(const float4*)(z + (size_t)p * 128 + ql * 8);
    const float4 zv1 = *(const float4*)(z + (size_t)p * 128 + ql * 8 + 4);
    float s = zv0.x + zv0.y + zv0.z + zv0.w + zv1.x + zv1.y + zv1.z + zv1.w;
    float sq = zv0.x * zv0.x + zv0.y * zv0.y + zv0.z * zv0.z + zv0.w * zv0.w
             + zv1.x * zv1.x + zv1.y * zv1.y + zv1.z * zv1.z + zv1.w * zv1.w;
    #pragma unroll
    for (int o = 8; o > 0; o >>= 1) { s += __shfl_xor(s, o); sq += __shfl_xor(sq, o); }
    const float mu = s * 0.0078125f;
    const float var = sq * 0.0078125f - mu * mu;
    const float rs = rsqrtf(var + 1e-5f);
    const int c0 = ql * 8;
    float zn[8];
    zn[0] = (zv0.x - mu) * rs * zg[c0 + 0] + zb[c0 + 0];
    zn[1] = (zv0.y - mu) * rs * zg[c0 + 1] + zb[c0 + 1];
    zn[2] = (zv0.z - mu) * rs * zg[c0 + 2] + zb[c0 + 2];
    zn[3] = (zv0.w - mu) * rs * zg[c0 + 3] + zb[c0 + 3];
    zn[4] = (zv1.x - mu) * rs * zg[c0 + 4] + zb[c0 + 4];
    zn[5] = (zv1.y - mu) * rs * zg[c0 + 5] + zb[c0 + 5];
    zn[6] = (zv1.z - mu) * rs * zg[c0 + 6] + zb[c0 + 6];
    zn[7] = (zv1.w - mu) * rs * zg[c0 + 7] + zb[c0 + 7];
    float a[8] = {};
    #pragma unroll
    for (int i = 0; i < 8; ++i) {
      #pragma unroll
      for (int hh = 0; hh < 8; ++hh) a[hh] += zn[i] * wz[(c0 + i) * 8 + hh];
    }
    #pragma unroll
    for (int hh = 0; hh < 8; ++hh) {
      #pragma unroll
      for (int o = 8; o > 0; o >>= 1) a[hh] += __shfl_xor(a[hh], o);
    }
    if (ql == 0) {
      const int i = p >> 8, j = p & 255;
      const int strip = i >> 5, il = i & 31, jt = j >> 5, r = j & 31;
      const int gh = (r >> 2) & 1, qd = r >> 3, c4 = r & 3;
      const int off = (strip * 8 + jt) * 1024 + (gh * 32 + il) * 16 + qd * 4 + c4;
      #pragma unroll
      for (int hh = 0; hh < 8; ++hh)
        pbp[(size_t)hh * 65536 + off] = a[hh] * LOG2E;
    }
  } else {
    // ---- LayerNorm(m) -> PACKED A-fragment layout
    const int lane = t & 63;
    const size_t row = (size_t)(b - 4176) * 4 + (t >> 6);
    const float4 xv = *(const float4*)(m + row * 256 + lane * 4);
    float s = xv.x + xv.y + xv.z + xv.w;
    float sq = xv.x * xv.x + xv.y * xv.y + xv.z * xv.z + xv.w * xv.w;
    #pragma unroll
    for (int o = 32; o > 0; o >>= 1) { s += __shfl_xor(s, o); sq += __shfl_xor(sq, o); }
    const float mu = s * 0.00390625f;
    const float var = sq * 0.00390625f - mu * mu;
    const float rs = rsqrtf(var + 1e-5f);
    const int c = lane * 4;
    u16x4 o4;
    o4.x = f2b((xv.x - mu) * rs * gam[c] + bet[c]);
    o4.y = f2b((xv.y - mu) * rs * gam[c + 1] + bet[c + 1]);
    o4.z = f2b((xv.z - mu) * rs * gam[c + 2] + bet[c + 2]);
    o4.w = f2b((xv.w - mu) * rs * gam[c + 3] + bet[c + 3]);
    const size_t ss = row >> 8;
    const int rloc = (int)(row & 255);
    const int ch = rloc >> 5, il = rloc & 31;
    const size_t dst = ss * 65536 + (size_t)ch * 8192 + (size_t)(lane >> 2) * 512
                     + (size_t)(((lane >> 1) & 1) * 32 + il) * 8 + (lane & 1) * 4;
    *(u16x4*)&mlp[dst] = o4;
  }
}

// ---------------------------------------------------------------------------
// Kernel 1 (FUSED v8): 512 threads / 8 waves; one block per (s,h).
// Decode REVERTED to R17 (s=bid&127, h=bid>>7): consecutive blocks share h,
// XCD x sees only s%8==x slices of mlp (1MB/XCD) — R18's h-pinned decode
// forced full-mlp refetch per XCD (FETCH 7x). Keeps setprio + pbq prefetch.
__global__ __launch_bounds__(512, 4) void k_fused(
    const u16* __restrict__ mlp, const u16* __restrict__ wtp,
    const float* __restrict__ bg, const float* __restrict__ pbp,
    const float* __restrict__ mask, u16* __restrict__ go) {
  __shared__ u16 gP[256 * 32];     // 16KB gate park
  __shared__ u16 lQ[256 * 32];     // 16KB row-swizzled
  __shared__ u16 lK[256 * 32];     // 16KB
  __shared__ u16 lVt[32][276];     // 17.25KB V^T padded
  __shared__ float lMb[256];
  __shared__ float lL[8][32];
  const int bid = blockIdx.x;
  const int s = bid & 127, h = bid >> 7;   // R17 decode (mlp-locality)
  const int t = threadIdx.x;
  const int lane = t & 63, wave = t >> 6;
  const int il = lane & 31, gh = lane >> 5;
  const int z = wave >> 1, half = wave & 1;

  // B preload: weight slice for z (cols h*32..+31, K=256)
  const u16* Wb = wtp + (size_t)z * 65536 + (size_t)(2 * h + (il >> 4)) * 4096
                + gh * 128 + (il & 15) * 8;
  bf16x8 B[16];
  #pragma unroll
  for (int kc = 0; kc < 16; ++kc) B[kc] = *(const bf16x8*)&Wb[kc * 256];

  if (t < 256)
    lMb[t] = (LOG2E * 1e9f) * (mask[s * 256 + t] - 1.0f) - 24.0f;  // log2 + shift
  const float bgv = bg[h * 32 + il];
  const u16* Ab = mlp + (size_t)s * 65536 + (size_t)lane * 8;

  // ---- GEMM phase: 4 chunks per wave, barrier-free, coalesced A from L2
  #pragma unroll
  for (int cc = 0; cc < 4; ++cc) {
    const int c = half * 4 + cc;
    f32x16 a0 = {}, a1 = {};
    bf16x8 A0[8];
    #pragma unroll
    for (int kc = 0; kc < 8; ++kc)
      A0[kc] = *(const bf16x8*)&Ab[c * 8192 + kc * 512];
    __builtin_amdgcn_s_setprio(1);
    #pragma unroll
    for (int kc = 0; kc < 8; kc += 2) {
      a0 = __builtin_amdgcn_mfma_f32_32x32x16_bf16(A0[kc], B[kc], a0, 0, 0, 0);
      a1 = __builtin_amdgcn_mfma_f32_32x32x16_bf16(A0[kc + 1], B[kc + 1], a1, 0, 0, 0);
    }
    __builtin_amdgcn_s_setprio(0);
    bf16x8 A1[8];
    #pragma unroll
    for (int kc = 0; kc < 8; ++kc)
      A1[kc] = *(const bf16x8*)&Ab[c * 8192 + (kc + 8) * 512];
    __builtin_amdgcn_s_setprio(1);
    #pragma unroll
    for (int kc = 0; kc < 8; kc += 2) {
      a0 = __builtin_amdgcn_mfma_f32_32x32x16_bf16(A1[kc], B[kc + 8], a0, 0, 0, 0);
      a1 = __builtin_amdgcn_mfma_f32_32x32x16_bf16(A1[kc + 1], B[kc + 9], a1, 0, 0, 0);
    }
    __builtin_amdgcn_s_setprio(0);
    const f32x16 acc = a0 + a1;
    // D[row][col=il], row = (reg&3) + 8*(reg>>2) + 4*gh  (within chunk)
    if (z == 0) {            // Q scaled by (1/sqrt32)*LOG2E
      #pragma unroll
      for (int reg = 0; reg < 16; ++reg) {
        const int R = c * 32 + (reg & 3) + 8 * (reg >> 2) + 4 * gh;
        *(u16*)((char*)lQ + ((R * 64 + il * 2) ^ ((R & 7) << 4))) =
            f2b(acc[reg] * (0.17677669529663687f * LOG2E));
      }
    } else if (z == 1) {     // K
      #pragma unroll
      for (int reg = 0; reg < 16; ++reg) {
        const int R = c * 32 + (reg & 3) + 8 * (reg >> 2) + 4 * gh;
        *(u16*)((char*)lK + ((R * 64 + il * 2) ^ ((R & 7) << 4))) = f2b(acc[reg]);
      }
    } else if (z == 2) {     // V -> V^T
      #pragma unroll
      for (int reg = 0; reg < 16; ++reg) {
        const int R = c * 32 + (reg & 3) + 8 * (reg >> 2) + 4 * gh;
        lVt[il][R] = f2b(acc[reg]);
      }
    } else {                 // G = sigmoid(x+bg) -> LDS park
      #pragma unroll
      for (int reg = 0; reg < 16; ++reg) {
        const int R = c * 32 + (reg & 3) + 8 * (reg >> 2) + 4 * gh;
        const float x = acc[reg] + bgv;
        gP[R * 32 + il] = f2b(1.0f / (1.0f + __expf(-x)));
      }
    }
  }
  __syncthreads();   // lQ/lK/lVt/gP visible to all waves

  // ---- Attention phase: ONE strip (32 q-rows) per wave; 1-deep pbq prefetch
  {
    const int i0 = wave * 32;
    bf16x8 qf[2];
    #pragma unroll
    for (int kk = 0; kk < 2; ++kk) {
      const int row = i0 + il;
      qf[kk] = *(const bf16x8*)((const char*)lQ +
          ((row * 64 + (kk * 16 + gh * 8) * 2) ^ ((row & 7) << 4)));
    }
    const float* pbt = pbp + ((size_t)h * 8 + wave) * 8192 + lane * 16;

    f32x16 oacc0 = {}, oacc1 = {};
    float s0 = 0.f, s1 = 0.f, s2 = 0.f, s3 = 0.f;

    f32x4 pq0 = *(const f32x4*)&pbt[0];
    f32x4 pq1 = *(const f32x4*)&pbt[4];
    f32x4 pq2 = *(const f32x4*)&pbt[8];
    f32x4 pq3 = *(const f32x4*)&pbt[12];

    #pragma unroll
    for (int jt = 0; jt < 8; ++jt) {
      f32x4 pn0, pn1, pn2, pn3;
      if (jt < 7) {
        const float* pl = pbt + (jt + 1) * 1024;
        pn0 = *(const f32x4*)&pl[0];
        pn1 = *(const f32x4*)&pl[4];
        pn2 = *(const f32x4*)&pl[8];
        pn3 = *(const f32x4*)&pl[12];
      }
      f32x16 c;
      {
        const f32x4 mb0 = *(const f32x4*)&lMb[jt * 32 + 0 * 8 + gh * 4];
        const f32x4 mb1 = *(const f32x4*)&lMb[jt * 32 + 1 * 8 + gh * 4];
        const f32x4 mb2 = *(const f32x4*)&lMb[jt * 32 + 2 * 8 + gh * 4];
        const f32x4 mb3 = *(const f32x4*)&lMb[jt * 32 + 3 * 8 + gh * 4];
        #pragma unroll
        for (int c4 = 0; c4 < 4; ++c4) {
          c[0 * 4 + c4] = pq0[c4] + mb0[c4];
          c[1 * 4 + c4] = pq1[c4] + mb1[c4];
          c[2 * 4 + c4] = pq2[c4] + mb2[c4];
          c[3 * 4 + c4] = pq3[c4] + mb3[c4];
        }
      }
      const int krow = jt * 32 + il;
      const bf16x8 kf0 = *(const bf16x8*)((const char*)lK +
          ((krow * 64 + (gh * 8) * 2) ^ ((krow & 7) << 4)));
      const bf16x8 kf1 = *(const bf16x8*)((const char*)lK +
          ((krow * 64 + (16 + gh * 8) * 2) ^ ((krow & 7) << 4)));
      __builtin_amdgcn_s_setprio(1);
      c = __builtin_amdgcn_mfma_f32_32x32x16_bf16(kf0, qf[0], c, 0, 0, 0);
      c = __builtin_amdgcn_mfma_f32_32x32x16_bf16(kf1, qf[1], c, 0, 0, 0);
      __builtin_amdgcn_s_setprio(0);
      union PK { __bf16 h[4]; uint2 u; } pk[4];
      #pragma unroll
      for (int qd = 0; qd < 4; ++qd) {
        const float p0 = fexp2(c[qd * 4 + 0]);
        const float p1 = fexp2(c[qd * 4 + 1]);
        const float p2 = fexp2(c[qd * 4 + 2]);
        const float p3 = fexp2(c[qd * 4 + 3]);
        s0 += p0; s1 += p1; s2 += p2; s3 += p3;
        pk[qd].h[0] = (__bf16)p0; pk[qd].h[1] = (__bf16)p1;
        pk[qd].h[2] = (__bf16)p2; pk[qd].h[3] = (__bf16)p3;
      }
      const uint2 sA = gh ? pk[0].u : pk[1].u;
      uint2 rA; rA.x = __shfl_xor(sA.x, 32); rA.y = __shfl_xor(sA.y, 32);
      const uint2 sB = gh ? pk[2].u : pk[3].u;
      uint2 rB; rB.x = __shfl_xor(sB.x, 32); rB.y = __shfl_xor(sB.y, 32);
      union FR { uint2 u2[2]; bf16x8 v; } fa0, fa1;
      fa0.u2[0] = gh ? rA : pk[0].u;
      fa0.u2[1] = gh ? pk[1].u : rA;
      fa1.u2[0] = gh ? rB : pk[2].u;
      fa1.u2[1] = gh ? pk[3].u : rB;
      const bf16x8 vf0 = *(const bf16x8*)&lVt[il][jt * 32 + gh * 8];
      const bf16x8 vf1 = *(const bf16x8*)&lVt[il][jt * 32 + 16 + gh * 8];
      __builtin_amdgcn_s_setprio(1);
      oacc0 = __builtin_amdgcn_mfma_f32_32x32x16_bf16(fa0.v, vf0, oacc0, 0, 0, 0);
      oacc1 = __builtin_amdgcn_mfma_f32_32x32x16_bf16(fa1.v, vf1, oacc1, 0, 0, 0);
      __builtin_amdgcn_s_setprio(0);
      if (jt < 7) { pq0 = pn0; pq1 = pn1; pq2 = pn2; pq3 = pn3; }
    }

    float lsum = (s0 + s1) + (s2 + s3);
    lsum += __shfl_xor(lsum, 32);
    if (lane < 32) lL[wave][il] = 1.0f / lsum;

    #pragma unroll
    for (int qd = 0; qd < 4; ++qd) {
      const f32x4 invq = *(const f32x4*)&lL[wave][qd * 8 + gh * 4];
      #pragma unroll
      for (int c4 = 0; c4 < 4; ++c4) {
        const int iloc = qd * 8 + gh * 4 + c4;
        const size_t row = (size_t)s * 256 + i0 + iloc;
        const int col = h * 32 + il;
        const float ov = (oacc0[qd * 4 + c4] + oacc1[qd * 4 + c4]) * invq[c4];
        const float gv = bf2f(gP[(i0 + iloc) * 32 + il]);
        go[row * 256 + col] = f2b(gv * ov);
      }
    }
  }
}

// ---------------------------------------------------------------------------
// Kernel 2: out = go @ wo + bo. grid 1024: 32 rows x 256 cols. Unchanged.
__global__ __launch_bounds__(256, 4) void k_gemm_out(
    const u16* __restrict__ go, const u16* __restrict__ wop,
    const float* __restrict__ bo, float* __restrict__ out) {
  __shared__ u16 lA[32 * 256];
  const int t = threadIdx.x;
  const size_t row0 = (size_t)blockIdx.x * 32;
  const int lane = t & 63, wave = t >> 6;
  const u16* Wz = wop + (size_t)wave * 16384 + (size_t)lane * 8;
  u16x8 areg[4];
  #pragma unroll
  for (int i = 0; i < 4; ++i)
    areg[i] = *(const u16x8*)&go[(row0 + i * 8 + (t >> 5)) * 256 + (t & 31) * 8];
  bf16x8 B[4][4];
  #pragma unroll
  for (int kc = 0; kc < 4; ++kc) {
    #pragma unroll
    for (int nn = 0; nn < 4; ++nn)
      B[kc][nn] = *(const bf16x8*)&Wz[nn * 4096 + kc * 512];
  }
  __builtin_amdgcn_sched_barrier(0);
  #pragma unroll
  for (int i = 0; i < 4; ++i) {
    const int r = i * 8 + (t >> 5);
    const int c = (t & 31) * 8;
    *(u16x8*)((char*)lA + ((r * 512 + c * 2) ^ ((r & 7) << 4))) = areg[i];
  }
  __syncthreads();
  const int lrow = lane & 15, lg = lane >> 4;
  f32x4 acc[2][4] = {};
  #pragma unroll
  for (int kc = 0; kc < 4; ++kc) {
    bf16x8 af[2];
    #pragma unroll
    for (int mm = 0; mm < 2; ++mm) {
      const int row = mm * 16 + lrow;
      af[mm] = *(const bf16x8*)((const char*)lA +
          ((row * 512 + kc * 64 + lg * 16) ^ ((row & 7) << 4)));
    }
    #pragma unroll
    for (int mm = 0; mm < 2; ++mm) {
      #pragma unroll
      for (int nn = 0; nn < 4; ++nn)
        acc[mm][nn] = __builtin_amdgcn_mfma_f32_16x16x32_bf16(
            af[mm], B[kc][nn], acc[mm][nn], 0, 0, 0);
    }
  }
  #pragma unroll
  for (int kc = 0; kc < 4; ++kc) {
    #pragma unroll
    for (int nn = 0; nn < 4; ++nn)
      B[kc][nn] = *(const bf16x8*)&Wz[nn * 4096 + (kc + 4) * 512];
  }
  __builtin_amdgcn_sched_barrier(0);
  #pragma unroll
  for (int kc = 0; kc < 4; ++kc) {
    bf16x8 af[2];
    #pragma unroll
    for (int mm = 0; mm < 2; ++mm) {
      const int row = mm * 16 + lrow;
      af[mm] = *(const bf16x8*)((const char*)lA +
          ((row * 512 + (kc + 4) * 64 + lg * 16) ^ ((row & 7) << 4)));
    }
    #pragma unroll
    for (int mm = 0; mm < 2; ++mm) {
      #pragma unroll
      for (int nn = 0; nn < 4; ++nn)
        acc[mm][nn] = __builtin_amdgcn_mfma_f32_16x16x32_bf16(
            af[mm], B[kc][nn], acc[mm][nn], 0, 0, 0);
    }
  }
  const int wc = wave * 64, lg4 = lg * 4;
  #pragma unroll
  for (int mm = 0; mm < 2; ++mm) {
    #pragma unroll
    for (int nn = 0; nn < 4; ++nn) {
      const int col = wc + nn * 16 + lrow;
      #pragma unroll
      for (int jr = 0; jr < 4; ++jr) {
        const size_t row = row0 + mm * 16 + lg4 + jr;
        out[row * 256 + col] = acc[mm][nn][jr] + bo[col];
      }
    }
  }
}

// ---------------------------------------------------------------------------
extern "C" void kernel_launch(void* const* d_in, const int* in_sizes, int n_in,
                              void* d_out, int out_size, void* d_ws, size_t ws_size,
                              hipStream_t stream) {
  const float* m      = (const float*)d_in[0];
  const float* z      = (const float*)d_in[1];
  const float* mask   = (const float*)d_in[2];
  const float* ln_m_g = (const float*)d_in[3];
  const float* ln_m_b = (const float*)d_in[4];
  const float* ln_z_g = (const float*)d_in[5];
  const float* ln_z_b = (const float*)d_in[6];
  const float* w_z    = (const float*)d_in[7];
  const float* wq     = (const float*)d_in[8];
  const float* wk     = (const float*)d_in[9];
  const float* wv     = (const float*)d_in[10];
  const float* wg     = (const float*)d_in[11];
  const float* bg     = (const float*)d_in[12];
  const float* wo     = (const float*)d_in[13];
  const float* bo     = (const float*)d_in[14];
  float* out = (float*)d_out;

  char* w = (char*)d_ws;
  u16* wtp   = (u16*)w;   w += (size_t)5 * 65536 * 2;
  float* pbp = (float*)w; w += (size_t)8 * 65536 * 4;
  u16* mlp   = (u16*)w;   w += (size_t)32768 * 256 * 2;
  u16* gow   = (u16*)w;   w += (size_t)32768 * 256 * 2;

  k_pre      <<<12368, 256, 0, stream>>>(wq, wk, wv, wg, wo, wtp,
                                         z, ln_z_g, ln_z_b, w_z, pbp,
                                         m, ln_m_g, ln_m_b, mlp);
  k_fused    <<<1024, 512, 0, stream>>>(mlp, wtp, bg, pbp, mask, gow);
  k_gemm_out <<<1024, 256, 0, stream>>>(gow, wtp + (size_t)4 * 65536, bo, out);
}

// Round 20
// 112.877 us; speedup vs baseline: 1.4233x; 1.3386x over previous
//
#include <hip/hip_runtime.h>
#include <hip/hip_bf16.h>

typedef unsigned short u16;
typedef __bf16 bf16x8 __attribute__((ext_vector_type(8)));
typedef float f32x4 __attribute__((ext_vector_type(4)));
typedef float f32x16 __attribute__((ext_vector_type(16)));
typedef unsigned short u16x8 __attribute__((ext_vector_type(8)));
typedef unsigned short u16x4 __attribute__((ext_vector_type(4)));

// S=128, R=256, CM=256, CZ=128, H=8, HD=32
#define LOG2E 1.4426950408889634f

__device__ __forceinline__ u16 f2b(float f) {          // native HW bf16 cvt (RNE)
  union { __bf16 b; u16 u; } v; v.b = (__bf16)f; return v.u;
}
__device__ __forceinline__ float bf2f(u16 u) {
  union { unsigned u; float f; } v; v.u = ((unsigned)u) << 16;
  return v.f;
}
__device__ __forceinline__ float fexp2(float x) {      // 1 instr, hazard-safe
  return __builtin_amdgcn_exp2f(x);
}

// ---------------------------------------------------------------------------
// Kernel 0 (MERGED pre-pass): blocks [0,80) = weight pack (B-frag order);
// [80,4176) = pair bias (pre-scaled LOG2E, permuted); [4176,12368) =
// LayerNorm(m) -> bf16 PACKED in MFMA A-fragment order.
__global__ __launch_bounds__(256) void k_pre(
    const float* __restrict__ wq, const float* __restrict__ wk,
    const float* __restrict__ wv, const float* __restrict__ wg,
    const float* __restrict__ wo, u16* __restrict__ wtp,
    const float* __restrict__ z, const float* __restrict__ zg,
    const float* __restrict__ zb, const float* __restrict__ wz,
    float* __restrict__ pbp,
    const float* __restrict__ m, const float* __restrict__ gam,
    const float* __restrict__ bet, u16* __restrict__ mlp) {
  __shared__ float lt[64][68];
  const int b = blockIdx.x;
  const int t = threadIdx.x;
  if (b < 80) {
    const int widx = b >> 4;
    const int tid = b & 15;
    const int ri = (tid >> 2) * 64, ci = (tid & 3) * 64;
    const float* src = (widx == 0) ? wq : (widx == 1) ? wk : (widx == 2) ? wv
                      : (widx == 3) ? wg : wo;
    {
      const int r = t >> 2;
      #pragma unroll
      for (int i = 0; i < 4; ++i) {
        const int c = (t & 3) * 16 + i * 4;
        *(float4*)&lt[r][c] = *(const float4*)&src[(ri + r) * 256 + ci + c];
      }
    }
    __syncthreads();
    #pragma unroll
    for (int cc = 0; cc < 2; ++cc) {
      const int c = t + cc * 256;
      const int kb = c >> 8, cb = (c >> 6) & 3, lg = (c >> 4) & 3, lr = c & 15;
      u16x8 o;
      #pragma unroll
      for (int j = 0; j < 8; ++j) o[j] = f2b(lt[kb * 32 + lg * 8 + j][cb * 16 + lr]);
      const size_t idx = (size_t)widx * 65536 + (size_t)((ci >> 4) + cb) * 4096
                       + (size_t)((ri >> 5) + kb) * 512 + (size_t)(lg * 16 + lr) * 8;
      *(u16x8*)&wtp[idx] = o;
    }
  } else if (b < 4176) {
    const int lane = t & 63, wave = t >> 6;
    const int ql = lane & 15;
    const int p = (b - 80) * 16 + wave * 4 + (lane >> 4);
    const float4 zv0 = *(const float4*)(z + (size_t)p * 128 + ql * 8);
    const float4 zv1 = *(const float4*)(z + (size_t)p * 128 + ql * 8 + 4);
    float s = zv0.x + zv0.y + zv0.z + zv0.w + zv1.x + zv1.y + zv1.z + zv1.w;
    float sq = zv0.x * zv0.x + zv0.y * zv0.y + zv0.z * zv0.z + zv0.w * zv0.w
             + zv1.x * zv1.x + zv1.y * zv1.y + zv1.z * zv1.z + zv1.w * zv1.w;
    #pragma unroll
    for (int o = 8; o > 0; o >>= 1) { s += __shfl_xor(s, o); sq += __shfl_xor(sq, o); }
    const float mu = s * 0.0078125f;
    const float var = sq * 0.0078125f - mu * mu;
    const float rs = rsqrtf(var + 1e-5f);
    const int c0 = ql * 8;
    float zn[8];
    zn[0] = (zv0.x - mu) * rs * zg[c0 + 0] + zb[c0 + 0];
    zn[1] = (zv0.y - mu) * rs * zg[c0 + 1] + zb[c0 + 1];
    zn[2] = (zv0.z - mu) * rs * zg[c0 + 2] + zb[c0 + 2];
    zn[3] = (zv0.w - mu) * rs * zg[c0 + 3] + zb[c0 + 3];
    zn[4] = (zv1.x - mu) * rs * zg[c0 + 4] + zb[c0 + 4];
    zn[5] = (zv1.y - mu) * rs * zg[c0 + 5] + zb[c0 + 5];
    zn[6] = (zv1.z - mu) * rs * zg[c0 + 6] + zb[c0 + 6];
    zn[7] = (zv1.w - mu) * rs * zg[c0 + 7] + zb[c0 + 7];
    float a[8] = {};
    #pragma unroll
    for (int i = 0; i < 8; ++i) {
      #pragma unroll
      for (int hh = 0; hh < 8; ++hh) a[hh] += zn[i] * wz[(c0 + i) * 8 + hh];
    }
    #pragma unroll
    for (int hh = 0; hh < 8; ++hh) {
      #pragma unroll
      for (int o = 8; o > 0; o >>= 1) a[hh] += __shfl_xor(a[hh], o);
    }
    if (ql == 0) {
      const int i = p >> 8, j = p & 255;
      const int strip = i >> 5, il = i & 31, jt = j >> 5, r = j & 31;
      const int gh = (r >> 2) & 1, qd = r >> 3, c4 = r & 3;
      const int off = (strip * 8 + jt) * 1024 + (gh * 32 + il) * 16 + qd * 4 + c4;
      #pragma unroll
      for (int hh = 0; hh < 8; ++hh)
        pbp[(size_t)hh * 65536 + off] = a[hh] * LOG2E;
    }
  } else {
    // ---- LayerNorm(m) -> PACKED A-fragment layout
    const int lane = t & 63;
    const size_t row = (size_t)(b - 4176) * 4 + (t >> 6);
    const float4 xv = *(const float4*)(m + row * 256 + lane * 4);
    float s = xv.x + xv.y + xv.z + xv.w;
    float sq = xv.x * xv.x + xv.y * xv.y + xv.z * xv.z + xv.w * xv.w;
    #pragma unroll
    for (int o = 32; o > 0; o >>= 1) { s += __shfl_xor(s, o); sq += __shfl_xor(sq, o); }
    const float mu = s * 0.00390625f;
    const float var = sq * 0.00390625f - mu * mu;
    const float rs = rsqrtf(var + 1e-5f);
    const int c = lane * 4;
    u16x4 o4;
    o4.x = f2b((xv.x - mu) * rs * gam[c] + bet[c]);
    o4.y = f2b((xv.y - mu) * rs * gam[c + 1] + bet[c + 1]);
    o4.z = f2b((xv.z - mu) * rs * gam[c + 2] + bet[c + 2]);
    o4.w = f2b((xv.w - mu) * rs * gam[c + 3] + bet[c + 3]);
    const size_t ss = row >> 8;
    const int rloc = (int)(row & 255);
    const int ch = rloc >> 5, il = rloc & 31;
    const size_t dst = ss * 65536 + (size_t)ch * 8192 + (size_t)(lane >> 2) * 512
                     + (size_t)(((lane >> 1) & 1) * 32 + il) * 8 + (lane & 1) * 4;
    *(u16x4*)&mlp[dst] = o4;
  }
}

// ---------------------------------------------------------------------------
// Kernel 1 (FUSED, exact R17 body — best measured at 62.6 us):
// 512 threads / 8 waves; one block per (s,h), decode s=bid&127, h=bid>>7.
// GEMM: wave w -> z=w>>1, half=w&1, chunks half*4..+3, barrier-free,
// coalesced A from packed mlp. Q/K/V -> LDS, G -> LDS buffer gP.
// Attention: ONE 32-row strip per wave, inline pbp loads (NO prefetch —
// R18/R19's prefetch pushed VGPR+AGPR over the 128 cap -> scratch spills,
// +100MB FETCH/WRITE). No setprio.
__global__ __launch_bounds__(512, 4) void k_fused(
    const u16* __restrict__ mlp, const u16* __restrict__ wtp,
    const float* __restrict__ bg, const float* __restrict__ pbp,
    const float* __restrict__ mask, u16* __restrict__ go) {
  __shared__ u16 gP[256 * 32];     // 16KB gate park
  __shared__ u16 lQ[256 * 32];     // 16KB row-swizzled
  __shared__ u16 lK[256 * 32];     // 16KB
  __shared__ u16 lVt[32][276];     // 17.25KB V^T padded
  __shared__ float lMb[256];
  __shared__ float lL[8][32];
  const int bid = blockIdx.x;
  const int s = bid & 127, h = bid >> 7;
  const int t = threadIdx.x;
  const int lane = t & 63, wave = t >> 6;
  const int il = lane & 31, gh = lane >> 5;
  const int z = wave >> 1, half = wave & 1;

  // B preload: weight slice for z (cols h*32..+31, K=256)
  const u16* Wb = wtp + (size_t)z * 65536 + (size_t)(2 * h + (il >> 4)) * 4096
                + gh * 128 + (il & 15) * 8;
  bf16x8 B[16];
  #pragma unroll
  for (int kc = 0; kc < 16; ++kc) B[kc] = *(const bf16x8*)&Wb[kc * 256];

  if (t < 256)
    lMb[t] = (LOG2E * 1e9f) * (mask[s * 256 + t] - 1.0f) - 24.0f;  // log2 + shift
  const float bgv = bg[h * 32 + il];
  const u16* Ab = mlp + (size_t)s * 65536 + (size_t)lane * 8;

  // ---- GEMM phase: 4 chunks per wave, barrier-free, coalesced A from L2
  #pragma unroll
  for (int cc = 0; cc < 4; ++cc) {
    const int c = half * 4 + cc;
    f32x16 a0 = {}, a1 = {};
    bf16x8 A0[8];
    #pragma unroll
    for (int kc = 0; kc < 8; ++kc)
      A0[kc] = *(const bf16x8*)&Ab[c * 8192 + kc * 512];
    #pragma unroll
    for (int kc = 0; kc < 8; kc += 2) {
      a0 = __builtin_amdgcn_mfma_f32_32x32x16_bf16(A0[kc], B[kc], a0, 0, 0, 0);
      a1 = __builtin_amdgcn_mfma_f32_32x32x16_bf16(A0[kc + 1], B[kc + 1], a1, 0, 0, 0);
    }
    bf16x8 A1[8];
    #pragma unroll
    for (int kc = 0; kc < 8; ++kc)
      A1[kc] = *(const bf16x8*)&Ab[c * 8192 + (kc + 8) * 512];
    #pragma unroll
    for (int kc = 0; kc < 8; kc += 2) {
      a0 = __builtin_amdgcn_mfma_f32_32x32x16_bf16(A1[kc], B[kc + 8], a0, 0, 0, 0);
      a1 = __builtin_amdgcn_mfma_f32_32x32x16_bf16(A1[kc + 1], B[kc + 9], a1, 0, 0, 0);
    }
    const f32x16 acc = a0 + a1;
    // D[row][col=il], row = (reg&3) + 8*(reg>>2) + 4*gh  (within chunk)
    if (z == 0) {            // Q scaled by (1/sqrt32)*LOG2E
      #pragma unroll
      for (int reg = 0; reg < 16; ++reg) {
        const int R = c * 32 + (reg & 3) + 8 * (reg >> 2) + 4 * gh;
        *(u16*)((char*)lQ + ((R * 64 + il * 2) ^ ((R & 7) << 4))) =
            f2b(acc[reg] * (0.17677669529663687f * LOG2E));
      }
    } else if (z == 1) {     // K
      #pragma unroll
      for (int reg = 0; reg < 16; ++reg) {
        const int R = c * 32 + (reg & 3) + 8 * (reg >> 2) + 4 * gh;
        *(u16*)((char*)lK + ((R * 64 + il * 2) ^ ((R & 7) << 4))) = f2b(acc[reg]);
      }
    } else if (z == 2) {     // V -> V^T
      #pragma unroll
      for (int reg = 0; reg < 16; ++reg) {
        const int R = c * 32 + (reg & 3) + 8 * (reg >> 2) + 4 * gh;
        lVt[il][R] = f2b(acc[reg]);
      }
    } else {                 // G = sigmoid(x+bg) -> LDS park
      #pragma unroll
      for (int reg = 0; reg < 16; ++reg) {
        const int R = c * 32 + (reg & 3) + 8 * (reg >> 2) + 4 * gh;
        const float x = acc[reg] + bgv;
        gP[R * 32 + il] = f2b(1.0f / (1.0f + __expf(-x)));
      }
    }
  }
  __syncthreads();   // lQ/lK/lVt/gP visible to all waves

  // ---- Attention phase: ONE strip (32 q-rows) per wave
  {
    const int i0 = wave * 32;
    bf16x8 qf[2];
    #pragma unroll
    for (int kk = 0; kk < 2; ++kk) {
      const int row = i0 + il;
      qf[kk] = *(const bf16x8*)((const char*)lQ +
          ((row * 64 + (kk * 16 + gh * 8) * 2) ^ ((row & 7) << 4)));
    }
    const float* pbt = pbp + ((size_t)h * 8 + wave) * 8192 + lane * 16;

    f32x16 oacc0 = {}, oacc1 = {};
    float s0 = 0.f, s1 = 0.f, s2 = 0.f, s3 = 0.f;

    #pragma unroll 2
    for (int jt = 0; jt < 8; ++jt) {
      const float* pl = pbt + jt * 1024;
      f32x16 c;
      #pragma unroll
      for (int qd = 0; qd < 4; ++qd) {
        const f32x4 pbq = *(const f32x4*)&pl[qd * 4];
        const f32x4 mb4 = *(const f32x4*)&lMb[jt * 32 + qd * 8 + gh * 4];
        #pragma unroll
        for (int c4 = 0; c4 < 4; ++c4)
          c[qd * 4 + c4] = pbq[c4] + mb4[c4];
      }
      const int krow = jt * 32 + il;
      const bf16x8 kf0 = *(const bf16x8*)((const char*)lK +
          ((krow * 64 + (gh * 8) * 2) ^ ((krow & 7) << 4)));
      const bf16x8 kf1 = *(const bf16x8*)((const char*)lK +
          ((krow * 64 + (16 + gh * 8) * 2) ^ ((krow & 7) << 4)));
      c = __builtin_amdgcn_mfma_f32_32x32x16_bf16(kf0, qf[0], c, 0, 0, 0);
      c = __builtin_amdgcn_mfma_f32_32x32x16_bf16(kf1, qf[1], c, 0, 0, 0);
      union PK { __bf16 h[4]; uint2 u; } pk[4];
      #pragma unroll
      for (int qd = 0; qd < 4; ++qd) {
        const float p0 = fexp2(c[qd * 4 + 0]);
        const float p1 = fexp2(c[qd * 4 + 1]);
        const float p2 = fexp2(c[qd * 4 + 2]);
        const float p3 = fexp2(c[qd * 4 + 3]);
        s0 += p0; s1 += p1; s2 += p2; s3 += p3;
        pk[qd].h[0] = (__bf16)p0; pk[qd].h[1] = (__bf16)p1;
        pk[qd].h[2] = (__bf16)p2; pk[qd].h[3] = (__bf16)p3;
      }
      const uint2 sA = gh ? pk[0].u : pk[1].u;
      uint2 rA; rA.x = __shfl_xor(sA.x, 32); rA.y = __shfl_xor(sA.y, 32);
      const uint2 sB = gh ? pk[2].u : pk[3].u;
      uint2 rB; rB.x = __shfl_xor(sB.x, 32); rB.y = __shfl_xor(sB.y, 32);
      union FR { uint2 u2[2]; bf16x8 v; } fa0, fa1;
      fa0.u2[0] = gh ? rA : pk[0].u;
      fa0.u2[1] = gh ? pk[1].u : rA;
      fa1.u2[0] = gh ? rB : pk[2].u;
      fa1.u2[1] = gh ? pk[3].u : rB;
      const bf16x8 vf0 = *(const bf16x8*)&lVt[il][jt * 32 + gh * 8];
      const bf16x8 vf1 = *(const bf16x8*)&lVt[il][jt * 32 + 16 + gh * 8];
      oacc0 = __builtin_amdgcn_mfma_f32_32x32x16_bf16(fa0.v, vf0, oacc0, 0, 0, 0);
      oacc1 = __builtin_amdgcn_mfma_f32_32x32x16_bf16(fa1.v, vf1, oacc1, 0, 0, 0);
    }

    float lsum = (s0 + s1) + (s2 + s3);
    lsum += __shfl_xor(lsum, 32);
    if (lane < 32) lL[wave][il] = 1.0f / lsum;

    #pragma unroll
    for (int qd = 0; qd < 4; ++qd) {
      const f32x4 invq = *(const f32x4*)&lL[wave][qd * 8 + gh * 4];
      #pragma unroll
      for (int c4 = 0; c4 < 4; ++c4) {
        const int iloc = qd * 8 + gh * 4 + c4;
        const size_t row = (size_t)s * 256 + i0 + iloc;
        const int col = h * 32 + il;
        const float ov = (oacc0[qd * 4 + c4] + oacc1[qd * 4 + c4]) * invq[c4];
        const float gv = bf2f(gP[(i0 + iloc) * 32 + il]);
        go[row * 256 + col] = f2b(gv * ov);
      }
    }
  }
}

// ---------------------------------------------------------------------------
// Kernel 2: out = go @ wo + bo. grid 1024: 32 rows x 256 cols. Unchanged.
__global__ __launch_bounds__(256, 4) void k_gemm_out(
    const u16* __restrict__ go, const u16* __restrict__ wop,
    const float* __restrict__ bo, float* __restrict__ out) {
  __shared__ u16 lA[32 * 256];
  const int t = threadIdx.x;
  const size_t row0 = (size_t)blockIdx.x * 32;
  const int lane = t & 63, wave = t >> 6;
  const u16* Wz = wop + (size_t)wave * 16384 + (size_t)lane * 8;
  u16x8 areg[4];
  #pragma unroll
  for (int i = 0; i < 4; ++i)
    areg[i] = *(const u16x8*)&go[(row0 + i * 8 + (t >> 5)) * 256 + (t & 31) * 8];
  bf16x8 B[4][4];
  #pragma unroll
  for (int kc = 0; kc < 4; ++kc) {
    #pragma unroll
    for (int nn = 0; nn < 4; ++nn)
      B[kc][nn] = *(const bf16x8*)&Wz[nn * 4096 + kc * 512];
  }
  __builtin_amdgcn_sched_barrier(0);
  #pragma unroll
  for (int i = 0; i < 4; ++i) {
    const int r = i * 8 + (t >> 5);
    const int c = (t & 31) * 8;
    *(u16x8*)((char*)lA + ((r * 512 + c * 2) ^ ((r & 7) << 4))) = areg[i];
  }
  __syncthreads();
  const int lrow = lane & 15, lg = lane >> 4;
  f32x4 acc[2][4] = {};
  #pragma unroll
  for (int kc = 0; kc < 4; ++kc) {
    bf16x8 af[2];
    #pragma unroll
    for (int mm = 0; mm < 2; ++mm) {
      const int row = mm * 16 + lrow;
      af[mm] = *(const bf16x8*)((const char*)lA +
          ((row * 512 + kc * 64 + lg * 16) ^ ((row & 7) << 4)));
    }
    #pragma unroll
    for (int mm = 0; mm < 2; ++mm) {
      #pragma unroll
      for (int nn = 0; nn < 4; ++nn)
        acc[mm][nn] = __builtin_amdgcn_mfma_f32_16x16x32_bf16(
            af[mm], B[kc][nn], acc[mm][nn], 0, 0, 0);
    }
  }
  #pragma unroll
  for (int kc = 0; kc < 4; ++kc) {
    #pragma unroll
    for (int nn = 0; nn < 4; ++nn)
      B[kc][nn] = *(const bf16x8*)&Wz[nn * 4096 + (kc + 4) * 512];
  }
  __builtin_amdgcn_sched_barrier(0);
  #pragma unroll
  for (int kc = 0; kc < 4; ++kc) {
    bf16x8 af[2];
    #pragma unroll
    for (int mm = 0; mm < 2; ++mm) {
      const int row = mm * 16 + lrow;
      af[mm] = *(const bf16x8*)((const char*)lA +
          ((row * 512 + (kc + 4) * 64 + lg * 16) ^ ((row & 7) << 4)));
    }
    #pragma unroll
    for (int mm = 0; mm < 2; ++mm) {
      #pragma unroll
      for (int nn = 0; nn < 4; ++nn)
        acc[mm][nn] = __builtin_amdgcn_mfma_f32_16x16x32_bf16(
            af[mm], B[kc][nn], acc[mm][nn], 0, 0, 0);
    }
  }
  const int wc = wave * 64, lg4 = lg * 4;
  #pragma unroll
  for (int mm = 0; mm < 2; ++mm) {
    #pragma unroll
    for (int nn = 0; nn < 4; ++nn) {
      const int col = wc + nn * 16 + lrow;
      #pragma unroll
      for (int jr = 0; jr < 4; ++jr) {
        const size_t row = row0 + mm * 16 + lg4 + jr;
        out[row * 256 + col] = acc[mm][nn][jr] + bo[col];
      }
    }
  }
}

// ---------------------------------------------------------------------------
extern "C" void kernel_launch(void* const* d_in, const int* in_sizes, int n_in,
                              void* d_out, int out_size, void* d_ws, size_t ws_size,
                              hipStream_t stream) {
  const float* m      = (const float*)d_in[0];
  const float* z      = (const float*)d_in[1];
  const float* mask   = (const float*)d_in[2];
  const float* ln_m_g = (const float*)d_in[3];
  const float* ln_m_b = (const float*)d_in[4];
  const float* ln_z_g = (const float*)d_in[5];
  const float* ln_z_b = (const float*)d_in[6];
  const float* w_z    = (const float*)d_in[7];
  const float* wq     = (const float*)d_in[8];
  const float* wk     = (const float*)d_in[9];
  const float* wv     = (const float*)d_in[10];
  const float* wg     = (const float*)d_in[11];
  const float* bg     = (const float*)d_in[12];
  const float* wo     = (const float*)d_in[13];
  const float* bo     = (const float*)d_in[14];
  float* out = (float*)d_out;

  char* w = (char*)d_ws;
  u16* wtp   = (u16*)w;   w += (size_t)5 * 65536 * 2;
  float* pbp = (float*)w; w += (size_t)8 * 65536 * 4;
  u16* mlp   = (u16*)w;   w += (size_t)32768 * 256 * 2;
  u16* gow   = (u16*)w;   w += (size_t)32768 * 256 * 2;

  k_pre      <<<12368, 256, 0, stream>>>(wq, wk, wv, wg, wo, wtp,
                                         z, ln_z_g, ln_z_b, w_z, pbp,
                                         m, ln_m_g, ln_m_b, mlp);
  k_fused    <<<1024, 512, 0, stream>>>(mlp, wtp, bg, pbp, mask, gow);
  k_gemm_out <<<1024, 256, 0, stream>>>(gow, wtp + (size_t)4 * 65536, bo, out);
}

// Round 21
// 110.479 us; speedup vs baseline: 1.4542x; 1.0217x over previous
//
#include <hip/hip_runtime.h>
#include <hip/hip_bf16.h>

typedef unsigned short u16;
typedef __bf16 bf16x8 __attribute__((ext_vector_type(8)));
typedef float f32x4 __attribute__((ext_vector_type(4)));
typedef float f32x16 __attribute__((ext_vector_type(16)));
typedef unsigned short u16x8 __attribute__((ext_vector_type(8)));
typedef unsigned short u16x4 __attribute__((ext_vector_type(4)));

// S=128, R=256, CM=256, CZ=128, H=8, HD=32
#define LOG2E 1.4426950408889634f

__device__ __forceinline__ u16 f2b(float f) {          // native HW bf16 cvt (RNE)
  union { __bf16 b; u16 u; } v; v.b = (__bf16)f; return v.u;
}
__device__ __forceinline__ float bf2f(u16 u) {
  union { unsigned u; float f; } v; v.u = ((unsigned)u) << 16;
  return v.f;
}
__device__ __forceinline__ float fexp2(float x) {      // 1 instr, hazard-safe
  return __builtin_amdgcn_exp2f(x);
}

// ---------------------------------------------------------------------------
// Kernel 0 (MERGED pre-pass): blocks [0,80) = weight pack (B-frag order);
// [80,4176) = pair bias (pre-scaled LOG2E, permuted); [4176,5200) =
// LayerNorm(m) -> bf16 PACKED in MFMA A-fragment order, one block per
// 32-row chunk with COALESCED mlp writes (1KB/wave-store; old layout was
// 32x 16B scattered segments per store).
__global__ __launch_bounds__(256) void k_pre(
    const float* __restrict__ wq, const float* __restrict__ wk,
    const float* __restrict__ wv, const float* __restrict__ wg,
    const float* __restrict__ wo, u16* __restrict__ wtp,
    const float* __restrict__ z, const float* __restrict__ zg,
    const float* __restrict__ zb, const float* __restrict__ wz,
    float* __restrict__ pbp,
    const float* __restrict__ m, const float* __restrict__ gam,
    const float* __restrict__ bet, u16* __restrict__ mlp) {
  __shared__ float lt[64][68];
  __shared__ u16 lnv[32 * 256];    // 16KB normalized bf16 stage (swizzled)
  const int b = blockIdx.x;
  const int t = threadIdx.x;
  if (b < 80) {
    const int widx = b >> 4;
    const int tid = b & 15;
    const int ri = (tid >> 2) * 64, ci = (tid & 3) * 64;
    const float* src = (widx == 0) ? wq : (widx == 1) ? wk : (widx == 2) ? wv
                      : (widx == 3) ? wg : wo;
    {
      const int r = t >> 2;
      #pragma unroll
      for (int i = 0; i < 4; ++i) {
        const int c = (t & 3) * 16 + i * 4;
        *(float4*)&lt[r][c] = *(const float4*)&src[(ri + r) * 256 + ci + c];
      }
    }
    __syncthreads();
    #pragma unroll
    for (int cc = 0; cc < 2; ++cc) {
      const int c = t + cc * 256;
      const int kb = c >> 8, cb = (c >> 6) & 3, lg = (c >> 4) & 3, lr = c & 15;
      u16x8 o;
      #pragma unroll
      for (int j = 0; j < 8; ++j) o[j] = f2b(lt[kb * 32 + lg * 8 + j][cb * 16 + lr]);
      const size_t idx = (size_t)widx * 65536 + (size_t)((ci >> 4) + cb) * 4096
                       + (size_t)((ri >> 5) + kb) * 512 + (size_t)(lg * 16 + lr) * 8;
      *(u16x8*)&wtp[idx] = o;
    }
  } else if (b < 4176) {
    const int lane = t & 63, wave = t >> 6;
    const int ql = lane & 15;
    const int p = (b - 80) * 16 + wave * 4 + (lane >> 4);
    const float4 zv0 = *(const float4*)(z + (size_t)p * 128 + ql * 8);
    const float4 zv1 = *(const float4*)(z + (size_t)p * 128 + ql * 8 + 4);
    float s = zv0.x + zv0.y + zv0.z + zv0.w + zv1.x + zv1.y + zv1.z + zv1.w;
    float sq = zv0.x * zv0.x + zv0.y * zv0.y + zv0.z * zv0.z + zv0.w * zv0.w
             + zv1.x * zv1.x + zv1.y * zv1.y + zv1.z * zv1.z + zv1.w * zv1.w;
    #pragma unroll
    for (int o = 8; o > 0; o >>= 1) { s += __shfl_xor(s, o); sq += __shfl_xor(sq, o); }
    const float mu = s * 0.0078125f;
    const float var = sq * 0.0078125f - mu * mu;
    const float rs = rsqrtf(var + 1e-5f);
    const int c0 = ql * 8;
    float zn[8];
    zn[0] = (zv0.x - mu) * rs * zg[c0 + 0] + zb[c0 + 0];
    zn[1] = (zv0.y - mu) * rs * zg[c0 + 1] + zb[c0 + 1];
    zn[2] = (zv0.z - mu) * rs * zg[c0 + 2] + zb[c0 + 2];
    zn[3] = (zv0.w - mu) * rs * zg[c0 + 3] + zb[c0 + 3];
    zn[4] = (zv1.x - mu) * rs * zg[c0 + 4] + zb[c0 + 4];
    zn[5] = (zv1.y - mu) * rs * zg[c0 + 5] + zb[c0 + 5];
    zn[6] = (zv1.z - mu) * rs * zg[c0 + 6] + zb[c0 + 6];
    zn[7] = (zv1.w - mu) * rs * zg[c0 + 7] + zb[c0 + 7];
    float a[8] = {};
    #pragma unroll
    for (int i = 0; i < 8; ++i) {
      #pragma unroll
      for (int hh = 0; hh < 8; ++hh) a[hh] += zn[i] * wz[(c0 + i) * 8 + hh];
    }
    #pragma unroll
    for (int hh = 0; hh < 8; ++hh) {
      #pragma unroll
      for (int o = 8; o > 0; o >>= 1) a[hh] += __shfl_xor(a[hh], o);
    }
    if (ql == 0) {
      const int i = p >> 8, j = p & 255;
      const int strip = i >> 5, il = i & 31, jt = j >> 5, r = j & 31;
      const int gh = (r >> 2) & 1, qd = r >> 3, c4 = r & 3;
      const int off = (strip * 8 + jt) * 1024 + (gh * 32 + il) * 16 + qd * 4 + c4;
      #pragma unroll
      for (int hh = 0; hh < 8; ++hh)
        pbp[(size_t)hh * 65536 + off] = a[hh] * LOG2E;
    }
  } else {
    // ---- LayerNorm(m) -> packed mlp, COALESCED writes.
    // One block = one (s, chunk): 32 rows. 8 threads/row (sub = t&7),
    // thread cols = {sub*4 + k*32 : k=0..7} (4 floats each).
    const int bid2 = b - 4176;
    const int ss = bid2 >> 3, ch = bid2 & 7;
    const int il = t >> 3, sub = t & 7;
    const size_t rbase = ((size_t)ss * 256 + ch * 32 + il) * 256;
    float4 xv[8];
    float s = 0.f, sq = 0.f;
    #pragma unroll
    for (int k = 0; k < 8; ++k) {
      xv[k] = *(const float4*)&m[rbase + sub * 4 + k * 32];
      s += xv[k].x + xv[k].y + xv[k].z + xv[k].w;
      sq += xv[k].x * xv[k].x + xv[k].y * xv[k].y
          + xv[k].z * xv[k].z + xv[k].w * xv[k].w;
    }
    #pragma unroll
    for (int o = 4; o > 0; o >>= 1) { s += __shfl_xor(s, o); sq += __shfl_xor(sq, o); }
    const float mu = s * 0.00390625f;
    const float var = sq * 0.00390625f - mu * mu;
    const float rs = rsqrtf(var + 1e-5f);
    const int swz = (il & 7) << 4;
    #pragma unroll
    for (int k = 0; k < 8; ++k) {
      const int c = sub * 4 + k * 32;
      u16x4 o4;
      o4.x = f2b((xv[k].x - mu) * rs * gam[c] + bet[c]);
      o4.y = f2b((xv[k].y - mu) * rs * gam[c + 1] + bet[c + 1]);
      o4.z = f2b((xv[k].z - mu) * rs * gam[c + 2] + bet[c + 2]);
      o4.w = f2b((xv[k].w - mu) * rs * gam[c + 3] + bet[c + 3]);
      *(u16x4*)((char*)lnv + ((il * 512 + c * 2) ^ swz)) = o4;
    }
    __syncthreads();
    // pack phase: flat = i*2048 + t*8 (u16) -> consecutive 16B per lane.
    u16* dst = mlp + (size_t)ss * 65536 + (size_t)ch * 8192;
    #pragma unroll
    for (int i = 0; i < 4; ++i) {
      const int flat = i * 2048 + t * 8;
      const int kc = flat >> 9;
      const int rem = flat & 511;
      const int gh = rem >> 8, il2 = (rem >> 3) & 31;
      const int col = kc * 16 + gh * 8;
      const u16x8 v = *(const u16x8*)((const char*)lnv +
          ((il2 * 512 + col * 2) ^ ((il2 & 7) << 4)));
      *(u16x8*)&dst[flat] = v;
    }
  }
}

// ---------------------------------------------------------------------------
// Kernel 1 (FUSED, R17/R20 body — best measured at 62 us). Unchanged.
__global__ __launch_bounds__(512, 4) void k_fused(
    const u16* __restrict__ mlp, const u16* __restrict__ wtp,
    const float* __restrict__ bg, const float* __restrict__ pbp,
    const float* __restrict__ mask, u16* __restrict__ go) {
  __shared__ u16 gP[256 * 32];     // 16KB gate park
  __shared__ u16 lQ[256 * 32];     // 16KB row-swizzled
  __shared__ u16 lK[256 * 32];     // 16KB
  __shared__ u16 lVt[32][276];     // 17.25KB V^T padded
  __shared__ float lMb[256];
  __shared__ float lL[8][32];
  const int bid = blockIdx.x;
  const int s = bid & 127, h = bid >> 7;
  const int t = threadIdx.x;
  const int lane = t & 63, wave = t >> 6;
  const int il = lane & 31, gh = lane >> 5;
  const int z = wave >> 1, half = wave & 1;

  const u16* Wb = wtp + (size_t)z * 65536 + (size_t)(2 * h + (il >> 4)) * 4096
                + gh * 128 + (il & 15) * 8;
  bf16x8 B[16];
  #pragma unroll
  for (int kc = 0; kc < 16; ++kc) B[kc] = *(const bf16x8*)&Wb[kc * 256];

  if (t < 256)
    lMb[t] = (LOG2E * 1e9f) * (mask[s * 256 + t] - 1.0f) - 24.0f;  // log2 + shift
  const float bgv = bg[h * 32 + il];
  const u16* Ab = mlp + (size_t)s * 65536 + (size_t)lane * 8;

  // ---- GEMM phase: 4 chunks per wave, barrier-free, coalesced A from L2
  #pragma unroll
  for (int cc = 0; cc < 4; ++cc) {
    const int c = half * 4 + cc;
    f32x16 a0 = {}, a1 = {};
    bf16x8 A0[8];
    #pragma unroll
    for (int kc = 0; kc < 8; ++kc)
      A0[kc] = *(const bf16x8*)&Ab[c * 8192 + kc * 512];
    #pragma unroll
    for (int kc = 0; kc < 8; kc += 2) {
      a0 = __builtin_amdgcn_mfma_f32_32x32x16_bf16(A0[kc], B[kc], a0, 0, 0, 0);
      a1 = __builtin_amdgcn_mfma_f32_32x32x16_bf16(A0[kc + 1], B[kc + 1], a1, 0, 0, 0);
    }
    bf16x8 A1[8];
    #pragma unroll
    for (int kc = 0; kc < 8; ++kc)
      A1[kc] = *(const bf16x8*)&Ab[c * 8192 + (kc + 8) * 512];
    #pragma unroll
    for (int kc = 0; kc < 8; kc += 2) {
      a0 = __builtin_amdgcn_mfma_f32_32x32x16_bf16(A1[kc], B[kc + 8], a0, 0, 0, 0);
      a1 = __builtin_amdgcn_mfma_f32_32x32x16_bf16(A1[kc + 1], B[kc + 9], a1, 0, 0, 0);
    }
    const f32x16 acc = a0 + a1;
    if (z == 0) {            // Q scaled by (1/sqrt32)*LOG2E
      #pragma unroll
      for (int reg = 0; reg < 16; ++reg) {
        const int R = c * 32 + (reg & 3) + 8 * (reg >> 2) + 4 * gh;
        *(u16*)((char*)lQ + ((R * 64 + il * 2) ^ ((R & 7) << 4))) =
            f2b(acc[reg] * (0.17677669529663687f * LOG2E));
      }
    } else if (z == 1) {     // K
      #pragma unroll
      for (int reg = 0; reg < 16; ++reg) {
        const int R = c * 32 + (reg & 3) + 8 * (reg >> 2) + 4 * gh;
        *(u16*)((char*)lK + ((R * 64 + il * 2) ^ ((R & 7) << 4))) = f2b(acc[reg]);
      }
    } else if (z == 2) {     // V -> V^T
      #pragma unroll
      for (int reg = 0; reg < 16; ++reg) {
        const int R = c * 32 + (reg & 3) + 8 * (reg >> 2) + 4 * gh;
        lVt[il][R] = f2b(acc[reg]);
      }
    } else {                 // G = sigmoid(x+bg) -> LDS park
      #pragma unroll
      for (int reg = 0; reg < 16; ++reg) {
        const int R = c * 32 + (reg & 3) + 8 * (reg >> 2) + 4 * gh;
        const float x = acc[reg] + bgv;
        gP[R * 32 + il] = f2b(1.0f / (1.0f + __expf(-x)));
      }
    }
  }
  __syncthreads();   // lQ/lK/lVt/gP visible to all waves

  // ---- Attention phase: ONE strip (32 q-rows) per wave
  {
    const int i0 = wave * 32;
    bf16x8 qf[2];
    #pragma unroll
    for (int kk = 0; kk < 2; ++kk) {
      const int row = i0 + il;
      qf[kk] = *(const bf16x8*)((const char*)lQ +
          ((row * 64 + (kk * 16 + gh * 8) * 2) ^ ((row & 7) << 4)));
    }
    const float* pbt = pbp + ((size_t)h * 8 + wave) * 8192 + lane * 16;

    f32x16 oacc0 = {}, oacc1 = {};
    float s0 = 0.f, s1 = 0.f, s2 = 0.f, s3 = 0.f;

    #pragma unroll 2
    for (int jt = 0; jt < 8; ++jt) {
      const float* pl = pbt + jt * 1024;
      f32x16 c;
      #pragma unroll
      for (int qd = 0; qd < 4; ++qd) {
        const f32x4 pbq = *(const f32x4*)&pl[qd * 4];
        const f32x4 mb4 = *(const f32x4*)&lMb[jt * 32 + qd * 8 + gh * 4];
        #pragma unroll
        for (int c4 = 0; c4 < 4; ++c4)
          c[qd * 4 + c4] = pbq[c4] + mb4[c4];
      }
      const int krow = jt * 32 + il;
      const bf16x8 kf0 = *(const bf16x8*)((const char*)lK +
          ((krow * 64 + (gh * 8) * 2) ^ ((krow & 7) << 4)));
      const bf16x8 kf1 = *(const bf16x8*)((const char*)lK +
          ((krow * 64 + (16 + gh * 8) * 2) ^ ((krow & 7) << 4)));
      c = __builtin_amdgcn_mfma_f32_32x32x16_bf16(kf0, qf[0], c, 0, 0, 0);
      c = __builtin_amdgcn_mfma_f32_32x32x16_bf16(kf1, qf[1], c, 0, 0, 0);
      union PK { __bf16 h[4]; uint2 u; } pk[4];
      #pragma unroll
      for (int qd = 0; qd < 4; ++qd) {
        const float p0 = fexp2(c[qd * 4 + 0]);
        const float p1 = fexp2(c[qd * 4 + 1]);
        const float p2 = fexp2(c[qd * 4 + 2]);
        const float p3 = fexp2(c[qd * 4 + 3]);
        s0 += p0; s1 += p1; s2 += p2; s3 += p3;
        pk[qd].h[0] = (__bf16)p0; pk[qd].h[1] = (__bf16)p1;
        pk[qd].h[2] = (__bf16)p2; pk[qd].h[3] = (__bf16)p3;
      }
      const uint2 sA = gh ? pk[0].u : pk[1].u;
      uint2 rA; rA.x = __shfl_xor(sA.x, 32); rA.y = __shfl_xor(sA.y, 32);
      const uint2 sB = gh ? pk[2].u : pk[3].u;
      uint2 rB; rB.x = __shfl_xor(sB.x, 32); rB.y = __shfl_xor(sB.y, 32);
      union FR { uint2 u2[2]; bf16x8 v; } fa0, fa1;
      fa0.u2[0] = gh ? rA : pk[0].u;
      fa0.u2[1] = gh ? pk[1].u : rA;
      fa1.u2[0] = gh ? rB : pk[2].u;
      fa1.u2[1] = gh ? pk[3].u : rB;
      const bf16x8 vf0 = *(const bf16x8*)&lVt[il][jt * 32 + gh * 8];
      const bf16x8 vf1 = *(const bf16x8*)&lVt[il][jt * 32 + 16 + gh * 8];
      oacc0 = __builtin_amdgcn_mfma_f32_32x32x16_bf16(fa0.v, vf0, oacc0, 0, 0, 0);
      oacc1 = __builtin_amdgcn_mfma_f32_32x32x16_bf16(fa1.v, vf1, oacc1, 0, 0, 0);
    }

    float lsum = (s0 + s1) + (s2 + s3);
    lsum += __shfl_xor(lsum, 32);
    if (lane < 32) lL[wave][il] = 1.0f / lsum;

    #pragma unroll
    for (int qd = 0; qd < 4; ++qd) {
      const f32x4 invq = *(const f32x4*)&lL[wave][qd * 8 + gh * 4];
      #pragma unroll
      for (int c4 = 0; c4 < 4; ++c4) {
        const int iloc = qd * 8 + gh * 4 + c4;
        const size_t row = (size_t)s * 256 + i0 + iloc;
        const int col = h * 32 + il;
        const float ov = (oacc0[qd * 4 + c4] + oacc1[qd * 4 + c4]) * invq[c4];
        const float gv = bf2f(gP[(i0 + iloc) * 32 + il]);
        go[row * 256 + col] = f2b(gv * ov);
      }
    }
  }
}

// ---------------------------------------------------------------------------
// Kernel 2: out = go @ wo + bo. grid 1024: 32 rows x 256 cols. Unchanged.
__global__ __launch_bounds__(256, 4) void k_gemm_out(
    const u16* __restrict__ go, const u16* __restrict__ wop,
    const float* __restrict__ bo, float* __restrict__ out) {
  __shared__ u16 lA[32 * 256];
  const int t = threadIdx.x;
  const size_t row0 = (size_t)blockIdx.x * 32;
  const int lane = t & 63, wave = t >> 6;
  const u16* Wz = wop + (size_t)wave * 16384 + (size_t)lane * 8;
  u16x8 areg[4];
  #pragma unroll
  for (int i = 0; i < 4; ++i)
    areg[i] = *(const u16x8*)&go[(row0 + i * 8 + (t >> 5)) * 256 + (t & 31) * 8];
  bf16x8 B[4][4];
  #pragma unroll
  for (int kc = 0; kc < 4; ++kc) {
    #pragma unroll
    for (int nn = 0; nn < 4; ++nn)
      B[kc][nn] = *(const bf16x8*)&Wz[nn * 4096 + kc * 512];
  }
  __builtin_amdgcn_sched_barrier(0);
  #pragma unroll
  for (int i = 0; i < 4; ++i) {
    const int r = i * 8 + (t >> 5);
    const int c = (t & 31) * 8;
    *(u16x8*)((char*)lA + ((r * 512 + c * 2) ^ ((r & 7) << 4))) = areg[i];
  }
  __syncthreads();
  const int lrow = lane & 15, lg = lane >> 4;
  f32x4 acc[2][4] = {};
  #pragma unroll
  for (int kc = 0; kc < 4; ++kc) {
    bf16x8 af[2];
    #pragma unroll
    for (int mm = 0; mm < 2; ++mm) {
      const int row = mm * 16 + lrow;
      af[mm] = *(const bf16x8*)((const char*)lA +
          ((row * 512 + kc * 64 + lg * 16) ^ ((row & 7) << 4)));
    }
    #pragma unroll
    for (int mm = 0; mm < 2; ++mm) {
      #pragma unroll
      for (int nn = 0; nn < 4; ++nn)
        acc[mm][nn] = __builtin_amdgcn_mfma_f32_16x16x32_bf16(
            af[mm], B[kc][nn], acc[mm][nn], 0, 0, 0);
    }
  }
  #pragma unroll
  for (int kc = 0; kc < 4; ++kc) {
    #pragma unroll
    for (int nn = 0; nn < 4; ++nn)
      B[kc][nn] = *(const bf16x8*)&Wz[nn * 4096 + (kc + 4) * 512];
  }
  __builtin_amdgcn_sched_barrier(0);
  #pragma unroll
  for (int kc = 0; kc < 4; ++kc) {
    bf16x8 af[2];
    #pragma unroll
    for (int mm = 0; mm < 2; ++mm) {
      const int row = mm * 16 + lrow;
      af[mm] = *(const bf16x8*)((const char*)lA +
          ((row * 512 + (kc + 4) * 64 + lg * 16) ^ ((row & 7) << 4)));
    }
    #pragma unroll
    for (int mm = 0; mm < 2; ++mm) {
      #pragma unroll
      for (int nn = 0; nn < 4; ++nn)
        acc[mm][nn] = __builtin_amdgcn_mfma_f32_16x16x32_bf16(
            af[mm], B[kc][nn], acc[mm][nn], 0, 0, 0);
    }
  }
  const int wc = wave * 64, lg4 = lg * 4;
  #pragma unroll
  for (int mm = 0; mm < 2; ++mm) {
    #pragma unroll
    for (int nn = 0; nn < 4; ++nn) {
      const int col = wc + nn * 16 + lrow;
      #pragma unroll
      for (int jr = 0; jr < 4; ++jr) {
        const size_t row = row0 + mm * 16 + lg4 + jr;
        out[row * 256 + col] = acc[mm][nn][jr] + bo[col];
      }
    }
  }
}

// ---------------------------------------------------------------------------
extern "C" void kernel_launch(void* const* d_in, const int* in_sizes, int n_in,
                              void* d_out, int out_size, void* d_ws, size_t ws_size,
                              hipStream_t stream) {
  const float* m      = (const float*)d_in[0];
  const float* z      = (const float*)d_in[1];
  const float* mask   = (const float*)d_in[2];
  const float* ln_m_g = (const float*)d_in[3];
  const float* ln_m_b = (const float*)d_in[4];
  const float* ln_z_g = (const float*)d_in[5];
  const float* ln_z_b = (const float*)d_in[6];
  const float* w_z    = (const float*)d_in[7];
  const float* wq     = (const float*)d_in[8];
  const float* wk     = (const float*)d_in[9];
  const float* wv     = (const float*)d_in[10];
  const float* wg     = (const float*)d_in[11];
  const float* bg     = (const float*)d_in[12];
  const float* wo     = (const float*)d_in[13];
  const float* bo     = (const float*)d_in[14];
  float* out = (float*)d_out;

  char* w = (char*)d_ws;
  u16* wtp   = (u16*)w;   w += (size_t)5 * 65536 * 2;
  float* pbp = (float*)w; w += (size_t)8 * 65536 * 4;
  u16* mlp   = (u16*)w;   w += (size_t)32768 * 256 * 2;
  u16* gow   = (u16*)w;   w += (size_t)32768 * 256 * 2;

  k_pre      <<<5200, 256, 0, stream>>>(wq, wk, wv, wg, wo, wtp,
                                        z, ln_z_g, ln_z_b, w_z, pbp,
                                        m, ln_m_g, ln_m_b, mlp);
  k_fused    <<<1024, 512, 0, stream>>>(mlp, wtp, bg, pbp, mask, gow);
  k_gemm_out <<<1024, 256, 0, stream>>>(gow, wtp + (size_t)4 * 65536, bo, out);
}